// Round 2
// baseline (1127.545 us; speedup 1.0000x reference)
//
#include <hip/hip_runtime.h>

#define HIDDEN 5120
#define NEXP 160
#define CHUNK_BYTES 20480           // per 32-k chunk: 160 rows x 64B hi, then 160 x 64B lo
#define NCHUNK 160                  // 5120 / 32
#define WBYTES (CHUNK_BYTES * NCHUNK)   // 3,276,800 B of converted W in ws
#define LOGITS_FLOATS (32768UL * NEXP)  // one partial-logits buffer

typedef _Float16 f16;
typedef f16 f16x8 __attribute__((ext_vector_type(8)));
typedef float f32x4 __attribute__((ext_vector_type(4)));
typedef float f32x16 __attribute__((ext_vector_type(16)));

// ---------------- K0: W fp32 -> chunked f16 hi/lo (v = hi + lo/2048) ----------------
__global__ void k_convert_w(const float* __restrict__ W, unsigned char* __restrict__ W2) {
    int t = blockIdx.x * 256 + threadIdx.x;        // 102400 threads, 8 k-elems each
    int e  = t / (HIDDEN / 8);
    int k8 = (t - e * (HIDDEN / 8)) * 8;
    const float* src = W + (long)e * HIDDEN + k8;
    float4 v0 = *(const float4*)(src);
    float4 v1 = *(const float4*)(src + 4);
    float v[8] = {v0.x, v0.y, v0.z, v0.w, v1.x, v1.y, v1.z, v1.w};
    f16x8 hi, lo;
#pragma unroll
    for (int j = 0; j < 8; ++j) {
        f16 h = (f16)v[j];
        hi[j] = h;
        lo[j] = (f16)((v[j] - (float)h) * 2048.0f);
    }
    int kc = k8 >> 5;
    int ko = k8 & 31;
    unsigned char* base = W2 + (size_t)kc * CHUNK_BYTES + e * 64 + ko * 2;
    *(f16x8*)base = hi;
    *(f16x8*)(base + 10240) = lo;
}

// ---------------- K1: LDS-free split-f16 GEMM, 32x32x16 MFMA, K-split 2 ----------------
// 512 blocks x 256 thr. Block = (tile 0..255, khalf 0..1). Wave owns 32 rows, all 160
// experts, 80 K-chunks. B-fragments read directly from W2 (3.3 MB, L2-resident; each
// 20 KB chunk L1-resident). X read via non-temporal loads (no reuse; keeps W2 in L2).
// No LDS, no syncthreads: nothing to drain, compiler pipelines freely.
__global__ __launch_bounds__(256, 2)
void k_gemm(const float* __restrict__ X, const unsigned char* __restrict__ W2,
            float* __restrict__ part) {
    const int tid  = threadIdx.x;
    const int w    = tid >> 6;         // wave 0..3 -> 32-row band
    const int l    = tid & 63;
    const int c32  = l & 31;           // A row / B col within fragment
    const int hsel = l >> 5;           // k-half selector within a 16-k MFMA step

    const int tile  = blockIdx.x >> 1;
    const int khalf = blockIdx.x & 1;

    const long row = (long)tile * 128 + w * 32 + c32;
    const float* aptr = X + row * HIDDEN + khalf * 2560 + hsel * 8;
    // per-lane B base inside a chunk: expert c32 (per n-tile), k-offset 8*hsel
    const unsigned char* wbase =
        W2 + (size_t)(khalf * 80) * CHUNK_BYTES + c32 * 64 + hsel * 16;

    f32x16 acc0[5], acc1[5];
#pragma unroll
    for (int n = 0; n < 5; ++n) {
#pragma unroll
        for (int r = 0; r < 16; ++r) { acc0[n][r] = 0.f; acc1[n][r] = 0.f; }
    }

    // A prefetch: chunk 0 (16 floats/lane = k 0..7 and 16..23 at this lane's hsel)
    f32x4 a0 = __builtin_nontemporal_load((const f32x4*)(aptr));
    f32x4 a1 = __builtin_nontemporal_load((const f32x4*)(aptr + 4));
    f32x4 a2 = __builtin_nontemporal_load((const f32x4*)(aptr + 16));
    f32x4 a3 = __builtin_nontemporal_load((const f32x4*)(aptr + 20));

    for (int c = 0; c < 80; ++c) {
        // prefetch next chunk's A while computing this one
        f32x4 n0 = a0, n1 = a1, n2 = a2, n3 = a3;
        if (c + 1 < 80) {
            const float* ap = aptr + (c + 1) * 32;
            n0 = __builtin_nontemporal_load((const f32x4*)(ap));
            n1 = __builtin_nontemporal_load((const f32x4*)(ap + 4));
            n2 = __builtin_nontemporal_load((const f32x4*)(ap + 16));
            n3 = __builtin_nontemporal_load((const f32x4*)(ap + 20));
        }

        // convert A -> hi/lo f16 for the two 16-k MFMA steps
        float av[16] = {a0[0], a0[1], a0[2], a0[3], a1[0], a1[1], a1[2], a1[3],
                        a2[0], a2[1], a2[2], a2[3], a3[0], a3[1], a3[2], a3[3]};
        f16x8 ah0, al0, ah1, al1;
#pragma unroll
        for (int j = 0; j < 8; ++j) {
            f16 h0 = (f16)av[j];
            ah0[j] = h0;
            al0[j] = (f16)((av[j] - (float)h0) * 2048.0f);
            f16 h1 = (f16)av[8 + j];
            ah1[j] = h1;
            al1[j] = (f16)((av[8 + j] - (float)h1) * 2048.0f);
        }

        const unsigned char* cb = wbase + (size_t)c * CHUNK_BYTES;
#pragma unroll
        for (int n = 0; n < 5; ++n) {
            f16x8 bh0 = *(const f16x8*)(cb + n * 2048);
            f16x8 bh1 = *(const f16x8*)(cb + n * 2048 + 32);
            f16x8 bl0 = *(const f16x8*)(cb + n * 2048 + 10240);
            f16x8 bl1 = *(const f16x8*)(cb + n * 2048 + 10240 + 32);
            acc0[n] = __builtin_amdgcn_mfma_f32_32x32x16_f16(ah0, bh0, acc0[n], 0, 0, 0);
            acc0[n] = __builtin_amdgcn_mfma_f32_32x32x16_f16(ah1, bh1, acc0[n], 0, 0, 0);
            acc1[n] = __builtin_amdgcn_mfma_f32_32x32x16_f16(al0, bh0, acc1[n], 0, 0, 0);
            acc1[n] = __builtin_amdgcn_mfma_f32_32x32x16_f16(ah0, bl0, acc1[n], 0, 0, 0);
            acc1[n] = __builtin_amdgcn_mfma_f32_32x32x16_f16(al1, bh1, acc1[n], 0, 0, 0);
            acc1[n] = __builtin_amdgcn_mfma_f32_32x32x16_f16(ah1, bl1, acc1[n], 0, 0, 0);
        }
        a0 = n0; a1 = n1; a2 = n2; a3 = n3;

        // bound intra-block wave drift (L1 locality on the shared W2 chunk);
        // raw s_barrier only — no waitcnt attached, loads stay in flight
        if ((c & 7) == 7) __builtin_amdgcn_s_barrier();
    }

    // epilogue: partial logits = acc0 + acc1/2048
    // C/D 32x32 layout: col = lane&31, row = (reg&3) + 8*(reg>>2) + 4*(lane>>5)
    float* obase = part + (size_t)khalf * LOGITS_FLOATS;
    const long rbase = (long)tile * 128 + w * 32 + hsel * 4;
#pragma unroll
    for (int n = 0; n < 5; ++n) {
#pragma unroll
        for (int r = 0; r < 16; ++r) {
            const int rr = (r & 3) + 8 * (r >> 2);
            __builtin_nontemporal_store(
                acc0[n][r] + acc1[n][r] * (1.0f / 2048.0f),
                obase + (rbase + rr) * NEXP + n * 32 + c32);
        }
    }
}

// ---------------- K2: gate, 8 lanes per token; sums the two K-half partials ----------------
__global__ __launch_bounds__(256)
void k_gate(const float* __restrict__ part, float* __restrict__ out) {
    const int t = blockIdx.x * 256 + threadIdx.x;
    const int token = t >> 3;
    const int sub   = t & 7;                       // expert group id
    const float* rA = part + (long)token * NEXP + sub * 20;
    const float* rB = rA + LOGITS_FLOATS;

    float v[20];
#pragma unroll
    for (int i = 0; i < 5; ++i) {
        f32x4 x = *(const f32x4*)(rA + i * 4);
        f32x4 y = *(const f32x4*)(rB + i * 4);
#pragma unroll
        for (int j = 0; j < 4; ++j) v[i * 4 + j] = x[j] + y[j];
    }

    float gmax = -1e30f, s = 0.f;
#pragma unroll
    for (int i = 0; i < 20; ++i) {
        gmax = fmaxf(gmax, v[i]);
        s += __expf(v[i]);
    }

    // softmax denom over full row: width-8 shuffle sum
    s += __shfl_xor(s, 1, 8);
    s += __shfl_xor(s, 2, 8);
    s += __shfl_xor(s, 4, 8);
    const float denom = s;

    // top-3 groups by group-max logit; ties -> lower group index (lax.top_k)
    float g = gmax;
    int sel0, sel1, sel2;
#pragma unroll
    for (int r = 0; r < 3; ++r) {
        float bv = g; int bi = sub;
#pragma unroll
        for (int m = 1; m < 8; m <<= 1) {
            float ov = __shfl_xor(bv, m, 8);
            int   oi = __shfl_xor(bi, m, 8);
            if (ov > bv || (ov == bv && oi < bi)) { bv = ov; bi = oi; }
        }
        if (r == 0) sel0 = bi; else if (r == 1) sel1 = bi; else sel2 = bi;
        if (sub == bi) g = -1e30f;                 // knock my group out for next round
    }
    const bool selected = (sub == sel0) | (sub == sel1) | (sub == sel2);

    // per-lane sorted top-6 of my 20 values (desc); non-selected lanes stay at -inf
    float w6[6] = {-1e30f, -1e30f, -1e30f, -1e30f, -1e30f, -1e30f};
    if (selected) {
#pragma unroll
        for (int i = 0; i < 20; ++i) {
            float x = v[i];
            if (x > w6[5]) {
                w6[5] = x;
#pragma unroll
                for (int j = 5; j > 0; --j)
                    if (w6[j] > w6[j - 1]) { float tmp = w6[j - 1]; w6[j - 1] = w6[j]; w6[j] = tmp; }
            }
        }
    }

    // 6-round cross-lane tournament merge; ties -> lower group (lower expert index)
    float res0, res1, res2, res3, res4, res5;
#pragma unroll
    for (int r = 0; r < 6; ++r) {
        float bv = w6[0]; int bi = sub;
#pragma unroll
        for (int m = 1; m < 8; m <<= 1) {
            float ov = __shfl_xor(bv, m, 8);
            int   oi = __shfl_xor(bi, m, 8);
            if (ov > bv || (ov == bv && oi < bi)) { bv = ov; bi = oi; }
        }
        if (r == 0) res0 = bv; else if (r == 1) res1 = bv; else if (r == 2) res2 = bv;
        else if (r == 3) res3 = bv; else if (r == 4) res4 = bv; else res5 = bv;
        if (sub == bi) {                           // winner pops its head (static shifts)
            w6[0] = w6[1]; w6[1] = w6[2]; w6[2] = w6[3];
            w6[3] = w6[4]; w6[4] = w6[5]; w6[5] = -1e30f;
        }
    }

    // lanes 0..5 write result[sub]
    float mine = res0;
    if (sub == 1) mine = res1;
    else if (sub == 2) mine = res2;
    else if (sub == 3) mine = res3;
    else if (sub == 4) mine = res4;
    else if (sub == 5) mine = res5;
    if (sub < 6)
        out[(long)token * 6 + sub] = 16.0f * __expf(mine) / denom;
}

extern "C" void kernel_launch(void* const* d_in, const int* in_sizes, int n_in,
                              void* d_out, int out_size, void* d_ws, size_t ws_size,
                              hipStream_t stream) {
    const float* X = (const float*)d_in[0];        // hidden_states [32768, 5120] fp32
    const float* W = (const float*)d_in[1];        // kernel [160, 5120] fp32
    float* out = (float*)d_out;                    // [32768, 6] fp32

    unsigned char* ws = (unsigned char*)d_ws;
    unsigned char* W2 = ws;                        // 3,276,800 B converted W
    float* part = (float*)(ws + WBYTES);           // 2 x 20,971,520 B partial logits

    hipLaunchKernelGGL(k_convert_w, dim3(400),  dim3(256), 0, stream, W, W2);
    hipLaunchKernelGGL(k_gemm,      dim3(512),  dim3(256), 0, stream, X, W2, part);
    hipLaunchKernelGGL(k_gate,      dim3(1024), dim3(256), 0, stream, part, out);
}

// Round 3
// 1004.120 us; speedup vs baseline: 1.1229x; 1.1229x over previous
//
#include <hip/hip_runtime.h>

#define HIDDEN 5120
#define NEXP 160
#define CHUNK_BYTES 20480           // per 32-k chunk: 5 ntiles x [s0,s1] x [hi,lo] x 64 lanes x 16B
#define NCHUNK 160                  // 5120 / 32
#define KHALF 80                    // chunks per K-half
#define WBYTES (CHUNK_BYTES * NCHUNK)   // 3,276,800 B of converted W in ws
#define LOGITS_FLOATS (32768UL * NEXP)  // one partial-logits buffer

typedef _Float16 f16;
typedef f16 f16x8 __attribute__((ext_vector_type(8)));
typedef float f32x4 __attribute__((ext_vector_type(4)));
typedef float f32x16 __attribute__((ext_vector_type(16)));

__device__ __forceinline__ void async_copy16(const void* g, void* l) {
    __builtin_amdgcn_global_load_lds(
        (const __attribute__((address_space(1))) unsigned int*)g,
        (__attribute__((address_space(3))) unsigned int*)l,
        16, 0, 0);
}

// ---------------- K0: W fp32 -> f16 hi/lo (v = hi + lo/2048), MFMA-fragment layout ----
// Chunk kc holds k = kc*32..+31 for all 160 experts, laid out so a lane's ds_read of its
// B fragment is base + lane*16 (conflict-free, and global_load_lds stages it linearly):
//   offset(n, s, part, lane) = n*4096 + s*2048 + part*1024 + lane*16
// where lane = (e&31) + 32*hsel, e = n*32 + (e&31), k = kc*32 + s*16 + hsel*8 + j.
__global__ void k_convert_w(const float* __restrict__ W, unsigned char* __restrict__ W2) {
    int t = blockIdx.x * 256 + threadIdx.x;        // 102400 threads, 8 k-elems each
    int e  = t / (HIDDEN / 8);
    int k8 = (t - e * (HIDDEN / 8)) * 8;
    const float* src = W + (long)e * HIDDEN + k8;
    float4 v0 = *(const float4*)(src);
    float4 v1 = *(const float4*)(src + 4);
    float v[8] = {v0.x, v0.y, v0.z, v0.w, v1.x, v1.y, v1.z, v1.w};
    f16x8 hi, lo;
#pragma unroll
    for (int j = 0; j < 8; ++j) {
        f16 h = (f16)v[j];
        hi[j] = h;
        lo[j] = (f16)((v[j] - (float)h) * 2048.0f);
    }
    int kc   = k8 >> 5;
    int s    = (k8 >> 4) & 1;
    int hsel = (k8 >> 3) & 1;
    int n    = e >> 5;
    int lane = (e & 31) + hsel * 32;
    unsigned char* base = W2 + (size_t)kc * CHUNK_BYTES + n * 4096 + s * 2048 + lane * 16;
    *(f16x8*)base = hi;            // part 0
    *(f16x8*)(base + 1024) = lo;   // part 1
}

// ---------------- K1: LDS-staged 32x32x16 split-f16 GEMM, counted-vmcnt pipeline ------
// 512 blocks = 256 tiles (BM=128) x 2 K-halves. 4 waves x 32 rows. B double-buffered in
// 40 KB LDS via global_load_lds; per-chunk vmem group = 5 stages + 4 A-loads = 9 ops;
// steady-state wait is vmcnt(9) (next group stays in flight), drained to 0 only at end.
template <int CUR, bool LAST, bool PREFETCH>
__device__ __forceinline__ void gemm_step(
    int c, const float* aptr, const unsigned char* gstage, unsigned char* lstage,
    const unsigned char* lfrag, f32x4 (&a)[4], f32x16* acc0, f32x16* acc1)
{
    if constexpr (LAST) {
        asm volatile("s_waitcnt vmcnt(0)");
    } else {
        asm volatile("s_waitcnt vmcnt(9)");   // my group c done; group c+1 in flight
    }
    __builtin_amdgcn_sched_barrier(0);
    __builtin_amdgcn_s_barrier();             // all waves' stage(c) complete
    __builtin_amdgcn_sched_barrier(0);

    // convert A chunk c -> hi/lo f16 fragments (two 16-k steps)
    float av[16] = {a[0][0], a[0][1], a[0][2], a[0][3], a[1][0], a[1][1], a[1][2], a[1][3],
                    a[2][0], a[2][1], a[2][2], a[2][3], a[3][0], a[3][1], a[3][2], a[3][3]};
    f16x8 ah0, al0, ah1, al1;
#pragma unroll
    for (int j = 0; j < 8; ++j) {
        f16 h0 = (f16)av[j];
        ah0[j] = h0;
        al0[j] = (f16)((av[j] - (float)h0) * 2048.0f);
        f16 h1 = (f16)av[8 + j];
        ah1[j] = h1;
        al1[j] = (f16)((av[8 + j] - (float)h1) * 2048.0f);
    }

    const unsigned char* lb = lfrag + CUR * CHUNK_BYTES;
    __builtin_amdgcn_s_setprio(1);
#pragma unroll
    for (int n = 0; n < 5; ++n) {
        f16x8 bh0 = *(const f16x8*)(lb + n * 4096);           // step0 hi
        f16x8 bl0 = *(const f16x8*)(lb + n * 4096 + 1024);    // step0 lo
        f16x8 bh1 = *(const f16x8*)(lb + n * 4096 + 2048);    // step1 hi
        f16x8 bl1 = *(const f16x8*)(lb + n * 4096 + 3072);    // step1 lo
        acc0[n] = __builtin_amdgcn_mfma_f32_32x32x16_f16(ah0, bh0, acc0[n], 0, 0, 0);
        acc0[n] = __builtin_amdgcn_mfma_f32_32x32x16_f16(ah1, bh1, acc0[n], 0, 0, 0);
        acc1[n] = __builtin_amdgcn_mfma_f32_32x32x16_f16(al0, bh0, acc1[n], 0, 0, 0);
        acc1[n] = __builtin_amdgcn_mfma_f32_32x32x16_f16(ah0, bl0, acc1[n], 0, 0, 0);
        acc1[n] = __builtin_amdgcn_mfma_f32_32x32x16_f16(al1, bh1, acc1[n], 0, 0, 0);
        acc1[n] = __builtin_amdgcn_mfma_f32_32x32x16_f16(ah1, bl1, acc1[n], 0, 0, 0);
    }
    __builtin_amdgcn_s_setprio(0);

    if constexpr (!LAST) {
        __builtin_amdgcn_s_barrier();         // all waves done reading buf[CUR]
        __builtin_amdgcn_sched_barrier(0);
        if constexpr (PREFETCH) {
            // issue group c+2 into buf[CUR] (freed above): 5 stages + 4 A-loads
            const unsigned char* gs = gstage + (size_t)(c + 2) * CHUNK_BYTES;
            unsigned char* ls = lstage + CUR * CHUNK_BYTES;
#pragma unroll
            for (int i = 0; i < 5; ++i)
                async_copy16(gs + i * 4096, ls + i * 4096);
            const float* ap = aptr + (c + 2) * 32;
            a[0] = __builtin_nontemporal_load((const f32x4*)(ap));
            a[1] = __builtin_nontemporal_load((const f32x4*)(ap + 4));
            a[2] = __builtin_nontemporal_load((const f32x4*)(ap + 16));
            a[3] = __builtin_nontemporal_load((const f32x4*)(ap + 20));
        }
        __builtin_amdgcn_sched_barrier(0);
    }
}

__global__ __launch_bounds__(256, 2)
void k_gemm(const float* __restrict__ X, const unsigned char* __restrict__ W2,
            float* __restrict__ part) {
    __shared__ __align__(16) unsigned char lds[2 * CHUNK_BYTES];   // 40 KB double-buffered
    const int tid  = threadIdx.x;
    const int w    = tid >> 6;         // wave 0..3 -> 32-row band
    const int l    = tid & 63;
    const int c32  = l & 31;           // A row within band / B expert col
    const int hsel = l >> 5;           // k-slice selector (8 elems)

    const int tile  = blockIdx.x >> 1;
    const int khalf = blockIdx.x & 1;

    const long row = (long)tile * 128 + w * 32 + c32;
    const float* aptr = X + row * HIDDEN + khalf * 2560 + hsel * 8;
    const unsigned char* gstage = W2 + (size_t)(khalf * KHALF) * CHUNK_BYTES + tid * 16;
    unsigned char* lstage = lds + (tid & ~63) * 16;   // wave-uniform base (+lane*16 by HW)
    const unsigned char* lfrag = lds + (size_t)l * 16;

    f32x16 acc0[5], acc1[5];
#pragma unroll
    for (int n = 0; n < 5; ++n) {
#pragma unroll
        for (int r = 0; r < 16; ++r) { acc0[n][r] = 0.f; acc1[n][r] = 0.f; }
    }

    // prologue: issue group 0 (buf0) then group 1 (buf1), boundaries pinned
    f32x4 aE[4], aO[4];
#pragma unroll
    for (int i = 0; i < 5; ++i)
        async_copy16(gstage + i * 4096, lstage + i * 4096);
    aE[0] = __builtin_nontemporal_load((const f32x4*)(aptr));
    aE[1] = __builtin_nontemporal_load((const f32x4*)(aptr + 4));
    aE[2] = __builtin_nontemporal_load((const f32x4*)(aptr + 16));
    aE[3] = __builtin_nontemporal_load((const f32x4*)(aptr + 20));
    __builtin_amdgcn_sched_barrier(0);
#pragma unroll
    for (int i = 0; i < 5; ++i)
        async_copy16(gstage + CHUNK_BYTES + i * 4096, lstage + CHUNK_BYTES + i * 4096);
    aO[0] = __builtin_nontemporal_load((const f32x4*)(aptr + 32));
    aO[1] = __builtin_nontemporal_load((const f32x4*)(aptr + 36));
    aO[2] = __builtin_nontemporal_load((const f32x4*)(aptr + 48));
    aO[3] = __builtin_nontemporal_load((const f32x4*)(aptr + 52));
    __builtin_amdgcn_sched_barrier(0);

    for (int c = 0; c < KHALF - 2; c += 2) {
        gemm_step<0, false, true>(c,     aptr, gstage, lstage, lfrag, aE, acc0, acc1);
        gemm_step<1, false, true>(c + 1, aptr, gstage, lstage, lfrag, aO, acc0, acc1);
    }
    gemm_step<0, false, false>(KHALF - 2, aptr, gstage, lstage, lfrag, aE, acc0, acc1);
    gemm_step<1, true,  false>(KHALF - 1, aptr, gstage, lstage, lfrag, aO, acc0, acc1);

    // epilogue: partial logits = acc0 + acc1/2048
    // C/D 32x32 layout: col = lane&31, row = (reg&3) + 8*(reg>>2) + 4*(lane>>5)
    float* obase = part + (size_t)khalf * LOGITS_FLOATS;
    const long rbase = (long)tile * 128 + w * 32 + hsel * 4;
#pragma unroll
    for (int n = 0; n < 5; ++n) {
#pragma unroll
        for (int r = 0; r < 16; ++r) {
            const int rr = (r & 3) + 8 * (r >> 2);
            __builtin_nontemporal_store(
                acc0[n][r] + acc1[n][r] * (1.0f / 2048.0f),
                obase + (rbase + rr) * NEXP + n * 32 + c32);
        }
    }
}

// ---------------- K2: gate, 8 lanes per token; sums the two K-half partials ----------------
__global__ __launch_bounds__(256)
void k_gate(const float* __restrict__ part, float* __restrict__ out) {
    const int t = blockIdx.x * 256 + threadIdx.x;
    const int token = t >> 3;
    const int sub   = t & 7;                       // expert group id
    const float* rA = part + (long)token * NEXP + sub * 20;
    const float* rB = rA + LOGITS_FLOATS;

    float v[20];
#pragma unroll
    for (int i = 0; i < 5; ++i) {
        f32x4 x = *(const f32x4*)(rA + i * 4);
        f32x4 y = *(const f32x4*)(rB + i * 4);
#pragma unroll
        for (int j = 0; j < 4; ++j) v[i * 4 + j] = x[j] + y[j];
    }

    float gmax = -1e30f, s = 0.f;
#pragma unroll
    for (int i = 0; i < 20; ++i) {
        gmax = fmaxf(gmax, v[i]);
        s += __expf(v[i]);
    }

    // softmax denom over full row: width-8 shuffle sum
    s += __shfl_xor(s, 1, 8);
    s += __shfl_xor(s, 2, 8);
    s += __shfl_xor(s, 4, 8);
    const float denom = s;

    // top-3 groups by group-max logit; ties -> lower group index (lax.top_k)
    float g = gmax;
    int sel0, sel1, sel2;
#pragma unroll
    for (int r = 0; r < 3; ++r) {
        float bv = g; int bi = sub;
#pragma unroll
        for (int m = 1; m < 8; m <<= 1) {
            float ov = __shfl_xor(bv, m, 8);
            int   oi = __shfl_xor(bi, m, 8);
            if (ov > bv || (ov == bv && oi < bi)) { bv = ov; bi = oi; }
        }
        if (r == 0) sel0 = bi; else if (r == 1) sel1 = bi; else sel2 = bi;
        if (sub == bi) g = -1e30f;                 // knock my group out for next round
    }
    const bool selected = (sub == sel0) | (sub == sel1) | (sub == sel2);

    // per-lane sorted top-6 of my 20 values (desc); non-selected lanes stay at -inf
    float w6[6] = {-1e30f, -1e30f, -1e30f, -1e30f, -1e30f, -1e30f};
    if (selected) {
#pragma unroll
        for (int i = 0; i < 20; ++i) {
            float x = v[i];
            if (x > w6[5]) {
                w6[5] = x;
#pragma unroll
                for (int j = 5; j > 0; --j)
                    if (w6[j] > w6[j - 1]) { float tmp = w6[j - 1]; w6[j - 1] = w6[j]; w6[j] = tmp; }
            }
        }
    }

    // 6-round cross-lane tournament merge; ties -> lower group (lower expert index)
    float res0, res1, res2, res3, res4, res5;
#pragma unroll
    for (int r = 0; r < 6; ++r) {
        float bv = w6[0]; int bi = sub;
#pragma unroll
        for (int m = 1; m < 8; m <<= 1) {
            float ov = __shfl_xor(bv, m, 8);
            int   oi = __shfl_xor(bi, m, 8);
            if (ov > bv || (ov == bv && oi < bi)) { bv = ov; bi = oi; }
        }
        if (r == 0) res0 = bv; else if (r == 1) res1 = bv; else if (r == 2) res2 = bv;
        else if (r == 3) res3 = bv; else if (r == 4) res4 = bv; else res5 = bv;
        if (sub == bi) {                           // winner pops its head (static shifts)
            w6[0] = w6[1]; w6[1] = w6[2]; w6[2] = w6[3];
            w6[3] = w6[4]; w6[4] = w6[5]; w6[5] = -1e30f;
        }
    }

    // lanes 0..5 write result[sub]
    float mine = res0;
    if (sub == 1) mine = res1;
    else if (sub == 2) mine = res2;
    else if (sub == 3) mine = res3;
    else if (sub == 4) mine = res4;
    else if (sub == 5) mine = res5;
    if (sub < 6)
        out[(long)token * 6 + sub] = 16.0f * __expf(mine) / denom;
}

extern "C" void kernel_launch(void* const* d_in, const int* in_sizes, int n_in,
                              void* d_out, int out_size, void* d_ws, size_t ws_size,
                              hipStream_t stream) {
    const float* X = (const float*)d_in[0];        // hidden_states [32768, 5120] fp32
    const float* W = (const float*)d_in[1];        // kernel [160, 5120] fp32
    float* out = (float*)d_out;                    // [32768, 6] fp32

    unsigned char* ws = (unsigned char*)d_ws;
    unsigned char* W2 = ws;                        // 3,276,800 B converted W
    float* part = (float*)(ws + WBYTES);           // 2 x 20,971,520 B partial logits

    hipLaunchKernelGGL(k_convert_w, dim3(400),  dim3(256), 0, stream, W, W2);
    hipLaunchKernelGGL(k_gemm,      dim3(512),  dim3(256), 0, stream, X, W2, part);
    hipLaunchKernelGGL(k_gate,      dim3(1024), dim3(256), 0, stream, part, out);
}